// Round 1
// baseline (298.022 us; speedup 1.0000x reference)
//
#include <hip/hip_runtime.h>
#include <math.h>

// EPG GRE F0 simulation: NP2=64 pulses, V voxels.
// State per voxel: K=32 complex triples (F+, F-, Z), k = 0..31.
// Exact truncation: level k matters at pulse p only if k <= min(p, 63-p, 31)
//  - k <= p      : states beyond p are exactly zero on ramp-up
//  - k <= 63-p   : information moves down at most one level per pulse (via F-),
//                  so higher states can never reach F0 by the last pulse.
// kmax in the reference is 32 but min(p,63-p) <= 31, so 32 states suffice.

#define NP2 64
#define KST 32

__global__ __launch_bounds__(64, 1) void epg_kernel(
    const float* __restrict__ theta_re,
    const float* __restrict__ theta_im,
    const float* __restrict__ TRp,
    const float* __restrict__ qmaps,
    float* __restrict__ out, int V)
{
    const int lane = threadIdx.x;
    const int v = blockIdx.x * 64 + lane;

    const float PD = qmaps[v];
    const float T1 = qmaps[V + v];
    const float T2 = qmaps[2 * V + v];
    const float tr = TRp[0];
    const float E1 = __expf(-tr / T1);
    const float E2 = __expf(-tr / T2);
    const float rE1 = 1.0f - E1;

    // State registers (fully unrolled access only -> stays in VGPRs)
    float Pr[KST], Pi[KST], Mr[KST], Mi[KST], Zr[KST], Zi[KST];
#pragma unroll
    for (int k = 0; k < KST; ++k) {
        Pr[k] = 0.f; Pi[k] = 0.f; Mr[k] = 0.f; Mi[k] = 0.f; Zr[k] = 0.f; Zi[k] = 0.f;
    }
    Zr[0] = 1.0f;

    __shared__ float buf[64][65];   // [local voxel][pulse], +1 pad: conflict-free

    for (int p = 0; p < NP2; ++p) {
        // ---- RF rotation matrix (wave-uniform; ~30 VALU ops) ----
        const float tre = theta_re[p], tim = theta_im[p];
        const float a2 = tre * tre + tim * tim;
        const float inva = __frsqrt_rn(a2);     // 1/|theta|  (|theta| >= 0.1)
        const float a = a2 * inva;              // |theta|
        const float c = tre * inva, s = tim * inva;   // cos(phi), sin(phi)
        float sa, ca;
        __sincosf(a, &sa, &ca);
        const float ca2 = 0.5f + 0.5f * ca;     // cos^2(a/2)
        const float sa2 = 0.5f - 0.5f * ca;     // sin^2(a/2)
        const float c2 = c * c - s * s;         // cos(2phi)
        const float s2 = 2.f * c * s;           // sin(2phi)
        const float r00 = ca2, r11 = ca2, r22 = ca;         // real diagonals
        const float r01r = c2 * sa2, r01i =  s2 * sa2;      // conj(e2m)*sa2
        const float r10r = c2 * sa2, r10i = -s2 * sa2;      // e2m*sa2
        const float r02r = s * sa,   r02i = -c * sa;        // -i*ep*sa
        const float r12r = s * sa,   r12i =  c * sa;        // +i*em*sa
        const float r20r = -0.5f * s * sa, r20i = -0.5f * c * sa;  // -0.5i*em*sa
        const float r21r = -0.5f * s * sa, r21i =  0.5f * c * sa;  // +0.5i*ep*sa

        const int b = min(min(p, 63 - p), KST - 1);   // live-state bound (uniform)

        float F0r = 0.f, F0i = 0.f;
        // ---- in-place RF: (P,M,Z)_k <- A @ (P,M,Z)_k for k <= b ----
#pragma unroll
        for (int k = 0; k < KST; ++k) {
            if (k <= b) {
                const float pr = Pr[k], pi = Pi[k];
                const float mr = Mr[k], mi = Mi[k];
                const float zr = Zr[k], zi = Zi[k];
                const float npr = r00 * pr + (r01r * mr - r01i * mi) + (r02r * zr - r02i * zi);
                const float npi = r00 * pi + (r01r * mi + r01i * mr) + (r02r * zi + r02i * zr);
                const float nmr = (r10r * pr - r10i * pi) + r11 * mr + (r12r * zr - r12i * zi);
                const float nmi = (r10r * pi + r10i * pr) + r11 * mi + (r12r * zi + r12i * zr);
                const float nzr = (r20r * pr - r20i * pi) + (r21r * mr - r21i * mi) + r22 * zr;
                const float nzi = (r20r * pi + r20i * pr) + (r21r * mi + r21i * mr) + r22 * zi;
                Pr[k] = npr; Pi[k] = npi;
                Mr[k] = nmr; Mi[k] = nmi;
                Zr[k] = nzr; Zi[k] = nzi;
                if (k == 0) { F0r = npr; F0i = npi; }
            }
        }
        buf[lane][p] = sqrtf(F0r * F0r + F0i * F0i) * PD;

        // ---- relaxation * shift + recovery ----
        const int bs = min(min(p + 1, 62 - p), KST - 1);  // states needed at pulse p+1
        const float t_r = E2 * Mr[1], t_i = E2 * Mi[1];   // capture M'_1 before overwrite
        // M: newM_k = E2 * M'_{k+1} (ascending, in place); M'_32 == 0 exactly
#pragma unroll
        for (int k = 1; k < KST; ++k) {
            if (k <= bs) {
                if (k < KST - 1) { Mr[k] = E2 * Mr[k + 1]; Mi[k] = E2 * Mi[k + 1]; }
                else             { Mr[k] = 0.f;            Mi[k] = 0.f; }
            }
        }
        // P: newP_k = E2 * P'_{k-1} (descending, in place)
#pragma unroll
        for (int k = KST - 1; k >= 1; --k) {
            if (k <= bs) { Pr[k] = E2 * Pr[k - 1]; Pi[k] = E2 * Pi[k - 1]; }
        }
        Pr[0] = t_r; Pi[0] = -t_i;   // conj(E2 * M'_1)
        Mr[0] = t_r; Mi[0] = t_i;    // E2 * M'_1
        // Z: newZ_k = E1 * Z'_k (+ recovery at k=0)
#pragma unroll
        for (int k = 0; k < KST; ++k) {
            if (k <= bs) { Zr[k] = E1 * Zr[k]; Zi[k] = E1 * Zi[k]; }
        }
        Zr[0] += rE1;
    }

    // ---- transpose via LDS -> coalesced [V, NP2] stores ----
    __syncthreads();
    const int vbase = blockIdx.x * 64;
#pragma unroll
    for (int r = 0; r < 64; ++r) {
        out[(vbase + r) * NP2 + lane] = buf[r][lane];
    }
}

extern "C" void kernel_launch(void* const* d_in, const int* in_sizes, int n_in,
                              void* d_out, int out_size, void* d_ws, size_t ws_size,
                              hipStream_t stream) {
    const float* theta_re = (const float*)d_in[0];
    const float* theta_im = (const float*)d_in[1];
    const float* TRp      = (const float*)d_in[2];
    const float* qmaps    = (const float*)d_in[3];
    float* out = (float*)d_out;
    const int V = in_sizes[3] / 3;          // qmaps is [3, V, 1]
    epg_kernel<<<dim3(V / 64), dim3(64), 0, stream>>>(theta_re, theta_im, TRp, qmaps, out, V);
}

// Round 2
// 155.197 us; speedup vs baseline: 1.9203x; 1.9203x over previous
//
#include <hip/hip_runtime.h>
#include <math.h>

// EPG GRE F0, NP2=64 pulses, V voxels.
// 4 lanes per voxel (quad), round-robin k: lane sub holds k = 4*j + sub, j<8.
// => 2048 waves (8/CU, 2/SIMD) instead of 512 (2/CU).
// Shift = DPP quad_perm rotation + boundary slot fixups (pure VALU).
// Exact truncation (matvec only where k <= min(p, 63-p, 31)):
//   up-ramp: k>p exactly zero; down-ramp: k>63-p can never reach F0.

#define NP2 64
#define SLOTS 8

// quad_perm: dest quad-lane i reads quad-lane perm[i].
// new(s) = old(s-1 mod 4): perm [3,0,1,2] -> 3|0<<2|1<<4|2<<6 = 0x93
// new(s) = old(s+1 mod 4): perm [1,2,3,0] -> 1|2<<2|3<<4|0<<6 = 0x39
template<int CTRL>
__device__ __forceinline__ float qperm(float x) {
    return __int_as_float(
        __builtin_amdgcn_mov_dpp(__float_as_int(x), CTRL, 0xF, 0xF, true));
}

__global__ __launch_bounds__(256, 2) void epg_kernel(
    const float* __restrict__ theta_re,
    const float* __restrict__ theta_im,
    const float* __restrict__ TRp,
    const float* __restrict__ qmaps,
    float* __restrict__ out, int V)
{
    const int t = threadIdx.x;
    const int sub = t & 3;          // quad lane: holds k = 4*j + sub
    const int vloc = t >> 2;        // 0..63 local voxel
    const int v = blockIdx.x * 64 + vloc;

    const float PD = qmaps[v];
    const float T1 = qmaps[V + v];
    const float T2 = qmaps[2 * V + v];
    const float tr = TRp[0];
    const float E1 = __expf(-tr / T1);
    const float E2 = __expf(-tr / T2);
    const float rE1s = (sub == 0) ? (1.0f - E1) : 0.0f;   // recovery only at k=0

    float Pr[SLOTS], Pi[SLOTS], Mr[SLOTS], Mi[SLOTS], Zr[SLOTS], Zi[SLOTS];
#pragma unroll
    for (int j = 0; j < SLOTS; ++j) {
        Pr[j] = 0.f; Pi[j] = 0.f; Mr[j] = 0.f; Mi[j] = 0.f; Zr[j] = 0.f; Zi[j] = 0.f;
    }
    if (sub == 0) Zr[0] = 1.0f;     // Z_0 = 1

    __shared__ float buf[64][68];   // [vloc][pulse], stride 68: 2-way banks (free)

    // software-pipelined theta loads (hide latency across the big body)
    float tre = theta_re[0], tim = theta_im[0];

    for (int p = 0; p < NP2; ++p) {
        const float tre_n = (p < NP2 - 1) ? theta_re[p + 1] : 0.f;
        const float tim_n = (p < NP2 - 1) ? theta_im[p + 1] : 0.f;

        // ---- RF rotation matrix (wave-uniform) ----
        const float a2 = tre * tre + tim * tim;
        const float inva = __frsqrt_rn(a2);
        const float a = a2 * inva;                     // |theta|
        const float c = tre * inva, s = tim * inva;    // cos(phi), sin(phi)
        float sa, ca;
        __sincosf(a, &sa, &ca);
        const float ca2 = 0.5f + 0.5f * ca;            // cos^2(a/2)
        const float sa2 = 0.5f - 0.5f * ca;            // sin^2(a/2)
        const float c2 = c * c - s * s;
        const float s2 = 2.f * c * s;
        const float r00 = ca2, r11 = ca2, r22 = ca;
        const float r01r = c2 * sa2, r01i =  s2 * sa2;
        const float r10r = c2 * sa2, r10i = -s2 * sa2;
        const float r02r = s * sa,   r02i = -c * sa;
        const float r12r = s * sa,   r12i =  c * sa;
        const float r20r = -0.5f * s * sa, r20i = -0.5f * c * sa;
        const float r21r = -0.5f * s * sa, r21i =  0.5f * c * sa;

        const int b = min(min(p, 63 - p), 31);   // live-state bound (uniform)

        // ---- RF matvec on live slots (uniform slot guard; lanes beyond b
        //      hold exact zeros (up-ramp) or irrelevant values (down-ramp)) ----
#pragma unroll
        for (int j = 0; j < SLOTS; ++j) {
            if (4 * j <= b) {
                const float pr = Pr[j], pi = Pi[j];
                const float mr = Mr[j], mi = Mi[j];
                const float zr = Zr[j], zi = Zi[j];
                const float npr = r00 * pr + (r01r * mr - r01i * mi) + (r02r * zr - r02i * zi);
                const float npi = r00 * pi + (r01r * mi + r01i * mr) + (r02r * zi + r02i * zr);
                const float nmr = (r10r * pr - r10i * pi) + r11 * mr + (r12r * zr - r12i * zi);
                const float nmi = (r10r * pi + r10i * pr) + r11 * mi + (r12r * zi + r12i * zr);
                const float nzr = (r20r * pr - r20i * pi) + (r21r * mr - r21i * mi) + r22 * zr;
                const float nzi = (r20r * pi + r20i * pr) + (r21r * mi + r21i * mr) + r22 * zi;
                Pr[j] = npr; Pi[j] = npi;
                Mr[j] = nmr; Mi[j] = nmi;
                Zr[j] = nzr; Zi[j] = nzi;
            }
        }
        // F0 = P'_0 lives on sub 0, slot 0
        if (sub == 0) buf[vloc][p] = sqrtf(Pr[0] * Pr[0] + Pi[0] * Pi[0]) * PD;

        if (p < NP2 - 1) {
            // ---- relaxation (full width: zero stays zero, junk stays junk) ----
#pragma unroll
            for (int j = 0; j < SLOTS; ++j) {
                Pr[j] *= E2; Pi[j] *= E2;
                Mr[j] *= E2; Mi[j] *= E2;
                Zr[j] *= E1; Zi[j] *= E1;
            }
            Zr[0] += rE1s;

            // ---- shift via quad rotation ----
            float sPr[SLOTS], sPi[SLOTS], sMr[SLOTS], sMi[SLOTS];
#pragma unroll
            for (int j = 0; j < SLOTS; ++j) {
                sPr[j] = qperm<0x93>(Pr[j]);   // from sub-1
                sPi[j] = qperm<0x93>(Pi[j]);
                sMr[j] = qperm<0x39>(Mr[j]);   // from sub+1
                sMi[j] = qperm<0x39>(Mi[j]);
            }
            const bool s0 = (sub == 0);
            const bool s3 = (sub == 3);
            // P_k <- E2*P'_{k-1}: sub>=1 same slot; sub0 slot j-1; sub0 slot0 = conj(M_0^new)
#pragma unroll
            for (int j = SLOTS - 1; j >= 1; --j) {
                Pr[j] = s0 ? sPr[j - 1] : sPr[j];
                Pi[j] = s0 ? sPi[j - 1] : sPi[j];
            }
            Pr[0] = s0 ?  sMr[0] : sPr[0];     // conj(E2*M'_1) on sub0
            Pi[0] = s0 ? -sMi[0] : sPi[0];
            // M_k <- E2*M'_{k+1}: sub<=2 same slot; sub3 slot j+1 (M'_32 = 0)
#pragma unroll
            for (int j = 0; j < SLOTS; ++j) {
                const float mr = (j < SLOTS - 1) ? sMr[j + 1] : 0.f;
                const float mi = (j < SLOTS - 1) ? sMi[j + 1] : 0.f;
                Mr[j] = s3 ? mr : sMr[j];
                Mi[j] = s3 ? mi : sMi[j];
            }
        }
        tre = tre_n; tim = tim_n;
    }

    // ---- coalesced output: block writes 64 voxels x 64 pulses ----
    __syncthreads();
    float4* out4 = (float4*)out;
    const int base4 = blockIdx.x * 1024;       // 4096 floats / 4
#pragma unroll
    for (int i = 0; i < 4; ++i) {
        const int q = i * 256 + t;             // float4 index within block
        const int f = 4 * q;
        const int r = f >> 6;                  // voxel row
        const int c = f & 63;                  // pulse col (multiple of 4)
        float4 val;
        val.x = buf[r][c];
        val.y = buf[r][c + 1];
        val.z = buf[r][c + 2];
        val.w = buf[r][c + 3];
        out4[base4 + q] = val;
    }
}

extern "C" void kernel_launch(void* const* d_in, const int* in_sizes, int n_in,
                              void* d_out, int out_size, void* d_ws, size_t ws_size,
                              hipStream_t stream) {
    const float* theta_re = (const float*)d_in[0];
    const float* theta_im = (const float*)d_in[1];
    const float* TRp      = (const float*)d_in[2];
    const float* qmaps    = (const float*)d_in[3];
    float* out = (float*)d_out;
    const int V = in_sizes[3] / 3;             // qmaps is [3, V, 1]
    epg_kernel<<<dim3(V / 64), dim3(256), 0, stream>>>(theta_re, theta_im, TRp, qmaps, out, V);
}

// Round 3
// 143.219 us; speedup vs baseline: 2.0809x; 1.0836x over previous
//
#include <hip/hip_runtime.h>
#include <math.h>

// EPG GRE F0, NP2=64 pulses, V voxels.
// 8 lanes per voxel, round-robin k: lane sub (0..7) holds k = 8*j + sub, j<4.
// => 4096 waves (16/CU, 4 waves/SIMD) for latency hiding.
// Shift = __shfl (ds_bpermute, LDS pipe) rotation within the 8-lane group
// + slot fixups on the wrap lanes. RF matrices precomputed once into LDS
// (2 broadcast ds_read_b128 per pulse instead of ~30 VALU + 2 transcendentals).
// Exact truncation: matvec only where slot-min-level 8j <= b = min(p, 63-p):
//   up-ramp: levels > p are exactly zero; down-ramp: levels > 63-p can never
//   reach F0 (info moves down max one level per pulse) - junk stays in the
//   dead cone (P moves junk up, M moves it to level >= 63-p-? proof in r1/r2).

#define NP2 64
#define SLOTS 4

__global__ __launch_bounds__(256, 4) void epg_kernel(
    const float* __restrict__ theta_re,
    const float* __restrict__ theta_im,
    const float* __restrict__ TRp,
    const float* __restrict__ qmaps,
    float* __restrict__ out, int V)
{
    const int t = threadIdx.x;
    const int sub = t & 7;            // lane within voxel group: holds k = 8j+sub
    const int vloc = t >> 3;          // 0..31 local voxel
    const int v = blockIdx.x * 32 + vloc;
    const int lane = t & 63;
    const int grp = lane & 56;
    const int srcP = grp | ((sub + 7) & 7);   // pull from sub-1 (mod 8)
    const int srcM = grp | ((sub + 1) & 7);   // pull from sub+1 (mod 8)

    __shared__ __align__(16) float rf[NP2][8]; // [p]: ca2, ca, t1, t2, t3, t4, h3, h4
    __shared__ float buf[32][68];              // [vloc][pulse], stride 68 (bank spread)

    // ---- prologue: lane p computes pulse p's 8 RF coefficients ----
    if (t < NP2) {
        const float tre = theta_re[t], tim = theta_im[t];
        const float a2 = tre * tre + tim * tim;
        const float inva = __frsqrt_rn(a2);        // |theta| >= 0.1
        const float a = a2 * inva;
        const float c = tre * inva, s = tim * inva;
        float sa, ca;
        __sincosf(a, &sa, &ca);
        const float ca2 = 0.5f + 0.5f * ca;        // cos^2(a/2)
        const float sa2 = 0.5f - 0.5f * ca;        // sin^2(a/2)
        const float t1 = (c * c - s * s) * sa2;    // cos(2phi)*sa2
        const float t2 = (2.f * c * s) * sa2;      // sin(2phi)*sa2
        const float t3 = s * sa;
        const float t4 = c * sa;
        rf[t][0] = ca2; rf[t][1] = ca; rf[t][2] = t1; rf[t][3] = t2;
        rf[t][4] = t3;  rf[t][5] = t4; rf[t][6] = 0.5f * t3; rf[t][7] = 0.5f * t4;
    }

    const float PD = qmaps[v];
    const float T1 = qmaps[V + v];
    const float T2 = qmaps[2 * V + v];
    const float tr = TRp[0];
    const float E1 = __expf(-tr / T1);
    const float E2 = __expf(-tr / T2);
    const float rE1s = (sub == 0) ? (1.0f - E1) : 0.0f;   // recovery only at k=0

    float Pr[SLOTS], Pi[SLOTS], Mr[SLOTS], Mi[SLOTS], Zr[SLOTS], Zi[SLOTS];
#pragma unroll
    for (int j = 0; j < SLOTS; ++j) {
        Pr[j] = 0.f; Pi[j] = 0.f; Mr[j] = 0.f; Mi[j] = 0.f; Zr[j] = 0.f; Zi[j] = 0.f;
    }
    if (sub == 0) Zr[0] = 1.0f;       // Z_0 = 1

    __syncthreads();

    for (int p = 0; p < NP2; ++p) {
        const float4 c0 = *(const float4*)&rf[p][0];  // ca2, ca, t1, t2 (broadcast)
        const float4 c1 = *(const float4*)&rf[p][4];  // t3, t4, h3, h4
        const float ca2 = c0.x, ca = c0.y, t1 = c0.z, t2 = c0.w;
        const float t3 = c1.x, t4 = c1.y, h3 = c1.z, h4 = c1.w;

        const int b = min(p, 63 - p);     // live-level bound (wave-uniform)

        // ---- RF matvec on live slots ----
#pragma unroll
        for (int j = 0; j < SLOTS; ++j) {
            if (8 * j <= b) {
                const float pr = Pr[j], pi = Pi[j];
                const float mr = Mr[j], mi = Mi[j];
                const float zr = Zr[j], zi = Zi[j];
                const float npr =  ca2 * pr + t1 * mr - t2 * mi + t3 * zr + t4 * zi;
                const float npi =  ca2 * pi + t2 * mr + t1 * mi + t3 * zi - t4 * zr;
                const float nmr =  t1 * pr + t2 * pi + ca2 * mr + t3 * zr - t4 * zi;
                const float nmi = -t2 * pr + t1 * pi + ca2 * mi + t4 * zr + t3 * zi;
                const float nzr = -h3 * pr + h4 * pi - h3 * mr - h4 * mi + ca * zr;
                const float nzi = -h4 * pr - h3 * pi + h4 * mr - h3 * mi + ca * zi;
                Pr[j] = npr; Pi[j] = npi;
                Mr[j] = nmr; Mi[j] = nmi;
                Zr[j] = nzr; Zi[j] = nzi;
            }
        }
        // F0 = P'_0 lives on sub 0, slot 0
        if (sub == 0) buf[vloc][p] = sqrtf(Pr[0] * Pr[0] + Pi[0] * Pi[0]) * PD;

        if (p < NP2 - 1) {
            // ---- relaxation (full width: zeros stay zero, junk stays dead) ----
#pragma unroll
            for (int j = 0; j < SLOTS; ++j) {
                Pr[j] *= E2; Pi[j] *= E2;
                Mr[j] *= E2; Mi[j] *= E2;
                Zr[j] *= E1; Zi[j] *= E1;
            }
            Zr[0] += rE1s;

            // ---- shift via 8-lane rotation (ds_bpermute, off the VALU pipe) ----
            float rPr[SLOTS], rPi[SLOTS], rMr[SLOTS], rMi[SLOTS];
#pragma unroll
            for (int j = 0; j < SLOTS; ++j) {
                rPr[j] = __shfl(Pr[j], srcP, 64);
                rPi[j] = __shfl(Pi[j], srcP, 64);
                rMr[j] = __shfl(Mr[j], srcM, 64);
                rMi[j] = __shfl(Mi[j], srcM, 64);
            }
            const bool s0 = (sub == 0);
            const bool s7 = (sub == 7);
            // P_k <- E2*P'_{k-1}: sub>=1 same slot; sub0 slot j-1; sub0/slot0 = conj(new M_0)
#pragma unroll
            for (int j = SLOTS - 1; j >= 1; --j) {
                Pr[j] = s0 ? rPr[j - 1] : rPr[j];
                Pi[j] = s0 ? rPi[j - 1] : rPi[j];
            }
            Pr[0] = s0 ?  rMr[0] : rPr[0];     // conj(E2*M'_1) on sub0
            Pi[0] = s0 ? -rMi[0] : rPi[0];
            // M_k <- E2*M'_{k+1}: sub<=6 same slot; sub7 slot j+1 (M'_32 = 0 exactly)
#pragma unroll
            for (int j = 0; j < SLOTS - 1; ++j) {
                Mr[j] = s7 ? rMr[j + 1] : rMr[j];
                Mi[j] = s7 ? rMi[j + 1] : rMi[j];
            }
            Mr[SLOTS - 1] = s7 ? 0.f : rMr[SLOTS - 1];
            Mi[SLOTS - 1] = s7 ? 0.f : rMi[SLOTS - 1];
        }
    }

    // ---- coalesced output: block writes 32 voxels x 64 pulses ----
    __syncthreads();
    float4* out4 = (float4*)out;
    const int base4 = blockIdx.x * 512;        // 2048 floats / 4
#pragma unroll
    for (int i = 0; i < 2; ++i) {
        const int q = i * 256 + t;             // float4 index within block
        const int f = 4 * q;
        const int r = f >> 6;                  // voxel row
        const int c = f & 63;                  // pulse col (multiple of 4)
        float4 val;
        val.x = buf[r][c];
        val.y = buf[r][c + 1];
        val.z = buf[r][c + 2];
        val.w = buf[r][c + 3];
        out4[base4 + q] = val;
    }
}

extern "C" void kernel_launch(void* const* d_in, const int* in_sizes, int n_in,
                              void* d_out, int out_size, void* d_ws, size_t ws_size,
                              hipStream_t stream) {
    const float* theta_re = (const float*)d_in[0];
    const float* theta_im = (const float*)d_in[1];
    const float* TRp      = (const float*)d_in[2];
    const float* qmaps    = (const float*)d_in[3];
    float* out = (float*)d_out;
    const int V = in_sizes[3] / 3;             // qmaps is [3, V, 1]
    epg_kernel<<<dim3(V / 32), dim3(256), 0, stream>>>(theta_re, theta_im, TRp, qmaps, out, V);
}